// Round 1
// baseline (229.446 us; speedup 1.0000x reference)
//
#include <hip/hip_runtime.h>
#include <stdint.h>

#define AS1 __attribute__((address_space(1)))
#define AS3 __attribute__((address_space(3)))

typedef __bf16 bf16x8 __attribute__((ext_vector_type(8)));
typedef float f32x4 __attribute__((ext_vector_type(4)));

constexpr int NB = 8;     // batches
constexpr int N  = 2048;  // nodes
constexpr int F  = 128;   // features (in == out)

__device__ __forceinline__ void async16(const void* g, void* l) {
    // LDS dest is wave-uniform base + lane*16 (m104/m108); pass base without lane term.
    __builtin_amdgcn_global_load_lds((const AS1 void*)g, (AS3 void*)l, 16, 0, 0);
}

__device__ __forceinline__ unsigned short bf16r(float f) {
    unsigned u = __float_as_uint(f);
    return (unsigned short)((u + 0x7FFFu + ((u >> 16) & 1u)) >> 16);
}

// ---------------------------------------------------------------------------
// K1: Wh_t[b][o][n] (bf16) = sum_f h[b][n][f] * W[o][f]
// Block: 64 m-rows x 128 o-cols, 4 waves (2x2), wave tile 32x64.
// Fragments loaded directly from global (K=128 only; h/W are L1/L2-resident).
// ---------------------------------------------------------------------------
__global__ __launch_bounds__(256) void k1_wh(const float* __restrict__ h,
                                             const float* __restrict__ W,
                                             unsigned short* __restrict__ Wht) {
    const int tid  = threadIdx.x;
    const int lane = tid & 63, wid = tid >> 6;
    const int quad = lane >> 4, l15 = lane & 15;
    const int wm = wid >> 1, wn = wid & 1;
    const int m0 = blockIdx.x * 64;
    const int batch = m0 >> 11;
    const int nbase = m0 & 2047;

    f32x4 acc[2][4] = {};

#pragma unroll
    for (int kk = 0; kk < 4; ++kk) {
        const int k = kk * 32 + quad * 8;
        bf16x8 afr[2], bfr[4];
#pragma unroll
        for (int rt = 0; rt < 2; ++rt) {
            const float* src = h + (size_t)(m0 + wm * 32 + rt * 16 + l15) * F + k;
            float4 x0 = *(const float4*)src;
            float4 x1 = *(const float4*)(src + 4);
            afr[rt][0] = (__bf16)x0.x; afr[rt][1] = (__bf16)x0.y;
            afr[rt][2] = (__bf16)x0.z; afr[rt][3] = (__bf16)x0.w;
            afr[rt][4] = (__bf16)x1.x; afr[rt][5] = (__bf16)x1.y;
            afr[rt][6] = (__bf16)x1.z; afr[rt][7] = (__bf16)x1.w;
        }
#pragma unroll
        for (int ct = 0; ct < 4; ++ct) {
            const int o = wn * 64 + ct * 16 + l15;
            const float* src = W + (size_t)o * F + k;
            float4 x0 = *(const float4*)src;
            float4 x1 = *(const float4*)(src + 4);
            bfr[ct][0] = (__bf16)x0.x; bfr[ct][1] = (__bf16)x0.y;
            bfr[ct][2] = (__bf16)x0.z; bfr[ct][3] = (__bf16)x0.w;
            bfr[ct][4] = (__bf16)x1.x; bfr[ct][5] = (__bf16)x1.y;
            bfr[ct][6] = (__bf16)x1.z; bfr[ct][7] = (__bf16)x1.w;
        }
#pragma unroll
        for (int rt = 0; rt < 2; ++rt)
#pragma unroll
            for (int ct = 0; ct < 4; ++ct)
                acc[rt][ct] = __builtin_amdgcn_mfma_f32_16x16x32_bf16(
                    afr[rt], bfr[ct], acc[rt][ct], 0, 0, 0);
    }

    // C/D layout: col = lane&15, row = quad*4 + reg. Store transposed (o-major),
    // 4 consecutive n per lane -> one 8B store.
#pragma unroll
    for (int rt = 0; rt < 2; ++rt)
#pragma unroll
        for (int ct = 0; ct < 4; ++ct) {
            const int o  = wn * 64 + ct * 16 + l15;
            const int nl = nbase + wm * 32 + rt * 16 + quad * 4;
            ushort4 v;
            v.x = bf16r(acc[rt][ct][0]); v.y = bf16r(acc[rt][ct][1]);
            v.z = bf16r(acc[rt][ct][2]); v.w = bf16r(acc[rt][ct][3]);
            *(ushort4*)&Wht[(size_t)batch * F * N + (size_t)o * N + nl] = v;
        }
}

// ---------------------------------------------------------------------------
// K2: p[b][j] = exp( sum_o Wh_t[b][o][j] * a2[o] ).  2 nodes per thread.
// ---------------------------------------------------------------------------
__global__ __launch_bounds__(256) void k2_p(const unsigned short* __restrict__ Wht,
                                            const float* __restrict__ a,
                                            float* __restrict__ p) {
    const int gid = blockIdx.x * 256 + threadIdx.x;   // 0..8191
    const int b = gid >> 10;
    const int n = (gid & 1023) * 2;
    const unsigned short* base = Wht + (size_t)b * F * N + n;
    float a0 = 0.f, a1 = 0.f;
#pragma unroll 8
    for (int o = 0; o < F; ++o) {
        unsigned v = *(const unsigned*)(base + (size_t)o * N);
        float f0 = __uint_as_float(v << 16);
        float f1 = __uint_as_float(v & 0xFFFF0000u);
        float w = a[F + o];                            // a2 = a[0, F:]
        a0 += f0 * w;
        a1 += f1 * w;
    }
    p[b * N + n]     = expf(a0);
    p[b * N + n + 1] = expf(a1);
}

// ---------------------------------------------------------------------------
// K3: out[b][i][o] = (sum_j adj[b][i][j]*p[j]*Wh[b][j][o]) / (sum_j adj*p)
// Block tile 32(i) x 128(o), BK=64, 4 waves (2x2), wave tile 16x64.
// adj staged fp32 via global_load_lds with XOR-swizzled GLOBAL fetch so the
// forced base+lane*16 LDS layout gives only (free) 2-way bank conflicts.
// p folded into A fragment at convert time; denominator = MFMA vs ones-B.
// ---------------------------------------------------------------------------
__global__ __launch_bounds__(256, 2) void k3_attn(const float* __restrict__ adj,
                                                  const unsigned short* __restrict__ Wht,
                                                  const float* __restrict__ p,
                                                  float* __restrict__ out) {
    __shared__ __align__(16) float         At[2][32 * 64];   // 8 KB each
    __shared__ __align__(16) unsigned short Bt[2][128 * 64]; // 16 KB each
    __shared__ __align__(16) float         Pt[2][64];

    const int tid  = threadIdx.x;
    const int lane = tid & 63, wid = tid >> 6;
    const int quad = lane >> 4, l15 = lane & 15;
    const int wm = wid >> 1, wn = wid & 1;
    const int b  = blockIdx.x >> 6;
    const int i0 = (blockIdx.x & 63) * 32;

    const float* adjb          = adj + (size_t)b * N * N;
    const unsigned short* Bb   = Wht + (size_t)b * F * N;
    const float* pb            = p + b * N;

    auto stageA = [&](int buf, int j0) {
#pragma unroll
        for (int is = 0; is < 2; ++is) {
            int Fo  = wid * 1024 + is * 4096 + lane * 16;  // byte offset in 8KB tile
            int row = Fo >> 8;                             // 256 B rows (64 fp32)
            int cg  = ((Fo >> 4) & 15) ^ (row & 15);       // swizzled global 16B chunk
            const float* g = adjb + (size_t)(i0 + row) * N + j0 + cg * 4;
            async16(g, (char*)&At[buf][0] + wid * 1024 + is * 4096);
        }
    };
    auto stageB = [&](int buf, int j0) {
#pragma unroll
        for (int is = 0; is < 4; ++is) {
            int Fo = wid * 1024 + is * 4096 + lane * 16;   // byte offset in 16KB tile
            int o  = Fo >> 7;                              // 128 B rows (64 bf16)
            int cg = ((Fo >> 4) & 7) ^ (o & 7);
            const unsigned short* g = Bb + (size_t)o * N + j0 + cg * 8;
            async16(g, (char*)&Bt[buf][0] + wid * 1024 + is * 4096);
        }
    };

    f32x4 acc[4] = {};
    f32x4 dacc = {};
    const bf16x8 ones = {(__bf16)1.0f, (__bf16)1.0f, (__bf16)1.0f, (__bf16)1.0f,
                         (__bf16)1.0f, (__bf16)1.0f, (__bf16)1.0f, (__bf16)1.0f};

    stageA(0, 0);
    stageB(0, 0);
    if (tid < 64) Pt[0][tid] = pb[tid];

    for (int ch = 0; ch < 32; ++ch) {
        const int cur = ch & 1, nxt = cur ^ 1;
        __syncthreads();   // drains chunk ch's loads; frees nxt buffer
        if (ch + 1 < 32) {
            stageA(nxt, (ch + 1) * 64);
            stageB(nxt, (ch + 1) * 64);
            if (tid < 64) Pt[nxt][tid] = pb[(ch + 1) * 64 + tid];
        }
#pragma unroll
        for (int ss = 0; ss < 2; ++ss) {
            const float* pt = &Pt[cur][ss * 32 + quad * 8];
            float4 pp0 = *(const float4*)pt;        // broadcast within quad
            float4 pp1 = *(const float4*)(pt + 4);

            const int r = wm * 16 + l15;
            const float* arow = &At[cur][r * 64];
            const int c0 = (ss * 8 + quad * 2)     ^ l15;
            const int c1 = (ss * 8 + quad * 2 + 1) ^ l15;
            float4 x0 = *(const float4*)(arow + c0 * 4);
            float4 x1 = *(const float4*)(arow + c1 * 4);

            bf16x8 af;  // A'[i][j] = adj * p[j], rounded to bf16 (adj in {0,1})
            af[0] = (__bf16)(x0.x * pp0.x); af[1] = (__bf16)(x0.y * pp0.y);
            af[2] = (__bf16)(x0.z * pp0.z); af[3] = (__bf16)(x0.w * pp0.w);
            af[4] = (__bf16)(x1.x * pp1.x); af[5] = (__bf16)(x1.y * pp1.y);
            af[6] = (__bf16)(x1.z * pp1.z); af[7] = (__bf16)(x1.w * pp1.w);

#pragma unroll
            for (int ct = 0; ct < 4; ++ct) {
                const int o  = wn * 64 + ct * 16 + l15;
                const int cb = (ss * 4 + quad) ^ (o & 7);
                bf16x8 bfv = *(const bf16x8*)((const char*)&Bt[cur][0] + o * 128 + cb * 16);
                acc[ct] = __builtin_amdgcn_mfma_f32_16x16x32_bf16(af, bfv, acc[ct], 0, 0, 0);
            }
            dacc = __builtin_amdgcn_mfma_f32_16x16x32_bf16(af, ones, dacc, 0, 0, 0);
        }
    }

    // dacc reg g holds denom for row quad*4+g (all 16 cols identical) — same
    // lane/row mapping as acc, so the divide is purely lane-local.
    float inv[4];
#pragma unroll
    for (int g = 0; g < 4; ++g) inv[g] = 1.0f / dacc[g];

    float* ob = out + (size_t)b * N * F;
#pragma unroll
    for (int ct = 0; ct < 4; ++ct) {
        const int o = wn * 64 + ct * 16 + l15;
#pragma unroll
        for (int g = 0; g < 4; ++g) {
            const int i = i0 + wm * 16 + quad * 4 + g;
            ob[(size_t)i * F + o] = acc[ct][g] * inv[g];
        }
    }
}

// ---------------------------------------------------------------------------
extern "C" void kernel_launch(void* const* d_in, const int* in_sizes, int n_in,
                              void* d_out, int out_size, void* d_ws, size_t ws_size,
                              hipStream_t stream) {
    const float* h   = (const float*)d_in[0];
    const float* adj = (const float*)d_in[1];
    const float* W   = (const float*)d_in[2];
    const float* a   = (const float*)d_in[3];
    float* out = (float*)d_out;

    unsigned short* Wht = (unsigned short*)d_ws;                       // 4 MB bf16
    float* p = (float*)((char*)d_ws + (size_t)4 * 1024 * 1024);        // 64 KB fp32

    k1_wh<<<NB * N / 64, 256, 0, stream>>>(h, W, Wht);
    k2_p<<<NB * N / (2 * 256), 256, 0, stream>>>(Wht, a, p);
    k3_attn<<<NB * (N / 32), 256, 0, stream>>>(adj, Wht, p, out);
}